// Round 6
// baseline (280.623 us; speedup 1.0000x reference)
//
#include <hip/hip_runtime.h>
#include <hip/hip_fp16.h>
#include <math.h>

// Problem constants
#define NN    100000
#define EPOS  250000
#define ENEG  250000
#define ENON  500000
#define E3   1000000
#define EHALF 500000
#define NLSE  4096

// k_edges phase split
#define NB_INFO   2816
#define NB_STRUCT 960
#define NB_NLL    320
#define NB_EDGES  (NB_INFO + NB_STRUCT + NB_NLL)

// Workspace layout (bytes, 16B-aligned sections)
#define ACC_OFF 0
#define LSE_OFF 256          // 65,536 -> 65,792
#define X0_OFF  66048        // 400,000 -> 466,048
#define ZA_OFF  466176       // 1.6M -> 2,066,176
#define ZB_OFF  2066176      // 1.6M -> 3,666,176
#define WT_OFF  3666176      // 272x104 bf16 = 56,576 -> 3,722,752
#define YF8_OFF 3722752      // 100k x 64 fp8 = 6.4M -> 10,122,752
#define PT_OFF  10122752     // 200,000 -> 10,322,752
#define QT_OFF  10322752     // 200,000 -> 10,522,752
#define PM_OFF  10522752     // 12.8M -> 23,322,752
#define QM_OFF  23322752     // 12.8M -> 36,122,752  (~36.2 MB total)

typedef __attribute__((ext_vector_type(8))) short bh8;
typedef __attribute__((ext_vector_type(4))) float f32x4;
typedef __attribute__((ext_vector_type(2))) float f32x2;

// acc slots: 0=nll, 1=l1_sum, 2=l2_sum, 3=s1(pred sum), 5/6 dummies

__device__ __forceinline__ unsigned short f2bf(float f) {
  unsigned u = __float_as_uint(f);
  unsigned r = (u + 0x7FFFu + ((u >> 16) & 1u)) >> 16;
  return (unsigned short)r;
}

#if __has_builtin(__builtin_amdgcn_cvt_pk_f32_bf8) && __has_builtin(__builtin_amdgcn_cvt_pk_bf8_f32)
#define HAVE_BF8 1
#endif

// Decode 4 packed bf8 (e5m2) bytes -> 4 floats.
__device__ __forceinline__ void de4(unsigned v, float* o) {
#ifdef HAVE_BF8
  f32x2 lo = __builtin_amdgcn_cvt_pk_f32_bf8((int)v, false);
  f32x2 hi = __builtin_amdgcn_cvt_pk_f32_bf8((int)v, true);
  o[0] = lo[0]; o[1] = lo[1]; o[2] = hi[0]; o[3] = hi[1];
#else
  o[0] = __half2float(__ushort_as_half((unsigned short)((v & 0xFFu) << 8)));
  o[1] = __half2float(__ushort_as_half((unsigned short)(((v >> 8) & 0xFFu) << 8)));
  o[2] = __half2float(__ushort_as_half((unsigned short)(((v >> 16) & 0xFFu) << 8)));
  o[3] = __half2float(__ushort_as_half((unsigned short)((v >> 24) << 8)));
#endif
}

// Encode 2 floats -> 2 bf8 bytes (low 16 bits), clamped to finite e5m2 range.
__device__ __forceinline__ unsigned pk2(float a, float b) {
  a = fminf(fmaxf(a, -57344.f), 57344.f);
  b = fminf(fmaxf(b, -57344.f), 57344.f);
#ifdef HAVE_BF8
  return (unsigned)__builtin_amdgcn_cvt_pk_bf8_f32(a, b, 0, false) & 0xFFFFu;
#else
  unsigned short ha = __half_as_ushort(__float2half(a));
  unsigned short hb = __half_as_ushort(__float2half(b));
  ha = (unsigned short)((ha + 0x7Fu + ((ha >> 8) & 1u)) >> 8);
  hb = (unsigned short)((hb + 0x7Fu + ((hb >> 8) & 1u)) >> 8);
  return (unsigned)ha | ((unsigned)hb << 8);
#endif
}

__device__ __forceinline__ void breduce2(double v0, double v1, double* g0, double* g1,
                                         double* rbuf) {
#pragma unroll
  for (int m = 32; m; m >>= 1) {
    v0 += __shfl_xor(v0, m, 64);
    v1 += __shfl_xor(v1, m, 64);
  }
  int l = threadIdx.x & 63, w = threadIdx.x >> 6;
  if (l == 0) { rbuf[2 * w] = v0; rbuf[2 * w + 1] = v1; }
  __syncthreads();
  if (threadIdx.x == 0) {
    int nw = blockDim.x >> 6;
    double s0 = 0.0, s1 = 0.0;
    for (int i = 0; i < nw; ++i) { s0 += rbuf[2 * i]; s1 += rbuf[2 * i + 1]; }
    atomicAdd(g0, s0);
    atomicAdd(g1, s1);
  }
}

__device__ __forceinline__ void lse_combine(double& m, double& s, double om, double os) {
  double M = fmax(m, om);
  double sn = 0.0;
  if (m > -INFINITY) sn += s * exp(m - M);
  if (om > -INFINITY) sn += os * exp(om - M);
  m = M;
  s = sn;
}

__device__ __forceinline__ void lse_block_reduce(double lm, double ls, double* out_pair,
                                                 double* rbuf) {
#pragma unroll
  for (int d = 32; d; d >>= 1) {
    double om = __shfl_xor(lm, d, 64);
    double os = __shfl_xor(ls, d, 64);
    lse_combine(lm, ls, om, os);
  }
  __syncthreads();
  int l = threadIdx.x & 63, w = threadIdx.x >> 6;
  if (l == 0) { rbuf[2 * w] = lm; rbuf[2 * w + 1] = ls; }
  __syncthreads();
  if (threadIdx.x == 0) {
    int nw = blockDim.x >> 6;
    double M = rbuf[0], S = rbuf[1];
    for (int i = 1; i < nw; ++i) lse_combine(M, S, rbuf[2 * i], rbuf[2 * i + 1]);
    out_pair[0] = M;
    out_pair[1] = S;
  }
}

// k_init: zero acc + lse pairs; build Wt_g [272 cols][104 k] bf16 (W-ext transposed).
// col c<130 -> P row c of w1; 136<=c<266 -> Q row (c-136); k<64 y coeff, k==64 x0 coeff.
__global__ __launch_bounds__(256) void k_init(const float* __restrict__ w1,
                                              double* __restrict__ acc,
                                              double* __restrict__ lse,
                                              unsigned short* __restrict__ wt) {
  int gid = blockIdx.x * 256 + threadIdx.x;
  if (gid < NLSE) { lse[2 * gid] = -INFINITY; lse[2 * gid + 1] = 0.0; }
  if (gid < 8) acc[gid] = 0.0;
  for (int u = threadIdx.x; u < 16 * 104; u += 256) {
    int c = 16 * blockIdx.x + u / 104;
    int k = u % 104;
    float val = 0.f;
    if (c < 130) {
      if (k < 64) val = w1[c * 131 + 1 + k];
      else if (k == 64) val = w1[c * 131];
    } else if (c >= 136 && c < 266) {
      int r = c - 136;
      if (k < 64) val = w1[r * 131 + 66 + k];
      else if (k == 64) val = w1[r * 131 + 65];
    }
    wt[(size_t)c * 104 + k] = f2bf(val);
  }
}

// k_pre: fused per-node precompute + PQ GEMM.
// Block = 128 threads = 128 nodes = 8 node-tiles. Phase 1: y -> LDS (bf16) + YF8/X0/ZA/ZB.
// Phase 2: per wave, tiles t=w,w+2,..: D[out][node] = Wext x Yext^T via
// mfma(A=W_frag, B=Y_frag) -> lane holds 4 consecutive outs for one node -> packed u32
// fp8 stores into Pm/Qm rows (and u16 tails PT/QT).
__global__ __launch_bounds__(128) void k_pre(
    const float* __restrict__ z, const float* __restrict__ lin_w,
    const unsigned short* __restrict__ wt,
    float* __restrict__ X0, unsigned char* __restrict__ YF8,
    float4* __restrict__ ZA4, float4* __restrict__ ZB4,
    unsigned char* __restrict__ Pm, unsigned char* __restrict__ Qm,
    unsigned char* __restrict__ PTb, unsigned char* __restrict__ QTb) {
  __shared__ float WL[384];
  __shared__ __align__(16) unsigned short YL[128 * 96];  // 24,576 B
  for (int u = threadIdx.x; u < 384; u += 128) {
    int rr = u >> 6, d = u & 63;
    WL[u] = (rr < 3) ? lin_w[rr * 128 + d] : lin_w[(rr - 3) * 128 + 64 + d];
  }
  __syncthreads();
  const int base = blockIdx.x * 128;
  const int n = base + threadIdx.x;
  if (n < NN) {
    const float4* zr = (const float4*)(z + (size_t)n * 64);
    const float4* wl4 = (const float4*)WL;
    float4 zc[16];
    float zn2 = 0.f, d0 = 0.f, d1 = 0.f, d2 = 0.f, d3 = 0.f, d4 = 0.f, d5 = 0.f;
#pragma unroll
    for (int c = 0; c < 16; ++c) {
      float4 v = zr[c];
      zc[c] = v;
      zn2 += v.x * v.x + v.y * v.y + v.z * v.z + v.w * v.w;
      float4 w0 = wl4[c];
      float4 w1r = wl4[16 + c];
      float4 w2r = wl4[32 + c];
      float4 w3 = wl4[48 + c];
      float4 w4 = wl4[64 + c];
      float4 w5 = wl4[80 + c];
      d0 += v.x * w0.x + v.y * w0.y + v.z * w0.z + v.w * w0.w;
      d1 += v.x * w1r.x + v.y * w1r.y + v.z * w1r.z + v.w * w1r.w;
      d2 += v.x * w2r.x + v.y * w2r.y + v.z * w2r.z + v.w * w2r.w;
      d3 += v.x * w3.x + v.y * w3.y + v.z * w3.z + v.w * w3.w;
      d4 += v.x * w4.x + v.y * w4.y + v.z * w4.z + v.w * w4.w;
      d5 += v.x * w5.x + v.y * w5.y + v.z * w5.z + v.w * w5.w;
    }
    float zn = fmaxf(sqrtf(zn2), 1e-15f);
    float t = 1.7320508075688772f * zn;
    float e = __expf(t);
    float sh = 0.5f * (e - __frcp_rn(e));
    float fac = (t < 1e-4f) ? (1.f + t * t * 0.16666667f) : (sh / t);
    float yn2 = fac * fac * zn2;
    float x0 = sqrtf(0.33333333333333333f + yn2);
    X0[n] = x0;
    ZA4[n] = make_float4(d0, d1, d2, 0.f);
    ZB4[n] = make_float4(d3, d4, d5, 0.f);
    unsigned short* yrow = YL + threadIdx.x * 96;
    unsigned yu[16];
#pragma unroll
    for (int c = 0; c < 16; ++c) {
      float4 v = zc[c];
      ushort4 o;
      o.x = f2bf(fac * v.x); o.y = f2bf(fac * v.y);
      o.z = f2bf(fac * v.z); o.w = f2bf(fac * v.w);
      *(ushort4*)(yrow + 4 * c) = o;
      yu[c] = pk2(fac * v.x, fac * v.y) | (pk2(fac * v.z, fac * v.w) << 16);
    }
    ushort4 xx; xx.x = f2bf(x0); xx.y = 0; xx.z = 0; xx.w = 0;
    *(ushort4*)(yrow + 64) = xx;
    ushort4 zz; zz.x = 0; zz.y = 0; zz.z = 0; zz.w = 0;
#pragma unroll
    for (int c = 17; c < 24; ++c) *(ushort4*)(yrow + 4 * c) = zz;
    uint4* y8 = (uint4*)(YF8 + (size_t)n * 64);
    y8[0] = make_uint4(yu[0], yu[1], yu[2], yu[3]);
    y8[1] = make_uint4(yu[4], yu[5], yu[6], yu[7]);
    y8[2] = make_uint4(yu[8], yu[9], yu[10], yu[11]);
    y8[3] = make_uint4(yu[12], yu[13], yu[14], yu[15]);
  }
  __syncthreads();
  // ---- phase 2: GEMM over this block's node tiles ----
  const int l = threadIdx.x & 63;
  const int w = threadIdx.x >> 6;
  const int col = l & 15, kq = l >> 4;
  const int ntiles = min(8, (NN - base) >> 4);
  for (int t = w; t < ntiles; t += 2) {
    const unsigned short* yr = YL + (t * 16 + col) * 96 + kq * 8;
    bh8 y0 = *(const bh8*)(yr);
    bh8 y1 = *(const bh8*)(yr + 32);
    bh8 y2 = *(const bh8*)(yr + 64);
    const size_t node = (size_t)(base + t * 16 + col);
#pragma unroll
    for (int nt = 0; nt < 17; ++nt) {
      const unsigned short* wr = wt + (size_t)(nt * 16 + col) * 104 + kq * 8;
      bh8 b0 = *(const bh8*)(wr);
      bh8 b1 = *(const bh8*)(wr + 32);
      bh8 b2 = *(const bh8*)(wr + 64);
      f32x4 a4 = {0.f, 0.f, 0.f, 0.f};
      a4 = __builtin_amdgcn_mfma_f32_16x16x32_bf16(b0, y0, a4, 0, 0, 0);
      a4 = __builtin_amdgcn_mfma_f32_16x16x32_bf16(b1, y1, a4, 0, 0, 0);
      a4 = __builtin_amdgcn_mfma_f32_16x16x32_bf16(b2, y2, a4, 0, 0, 0);
      // lane holds outs ob..ob+3 (ob = nt*16 + kq*4) for `node`
      int ob = nt * 16 + kq * 4;
      unsigned u = pk2(a4[0], a4[1]) | (pk2(a4[2], a4[3]) << 16);
      if (nt < 8) {
        *(unsigned*)(Pm + node * 128 + ob) = u;                    // P k=0..127
      } else if (nt == 8) {
        if (kq == 0) *(unsigned short*)(PTb + node * 2) = (unsigned short)pk2(a4[0], a4[1]);
        else if (kq >= 2) *(unsigned*)(Qm + node * 128 + (ob - 136)) = u;  // Q k=0..7
      } else if (nt < 16) {
        *(unsigned*)(Qm + node * 128 + (ob - 136)) = u;            // Q k=8..119
      } else {
        if (kq < 2) *(unsigned*)(Qm + node * 128 + (ob - 136)) = u;  // Q k=120..127
        else if (kq == 2) *(unsigned short*)(QTb + node * 2) = (unsigned short)pk2(a4[0], a4[1]);
      }
    }
  }
}

__device__ __forceinline__ float hsq(float mdot) {
  float th = fmaxf(-3.f * mdot, 1.f + 1e-7f);
  float ach = __logf(th + sqrtf(th * th - 1.f));
  return fminf(ach * ach * (1.f / 3.f), 50.f);
}

// k_edges: fused nll + struct + info, phase by block range.
__global__ __launch_bounds__(256) void k_edges(
    const int* __restrict__ p0, const int* __restrict__ p1,
    const int* __restrict__ n0, const int* __restrict__ n1,
    const int* __restrict__ o0, const int* __restrict__ o1,   // none (nll)
    const int* __restrict__ q0, const int* __restrict__ q1,   // none2 (info)
    const int* __restrict__ pk, const int* __restrict__ nk,
    const int* __restrict__ perm,
    const unsigned char* __restrict__ Pm, const unsigned char* __restrict__ Qm,
    const unsigned short* __restrict__ PT, const unsigned short* __restrict__ QT,
    const unsigned char* __restrict__ YF8, const float* __restrict__ X0,
    const float4* __restrict__ ZA4, const float4* __restrict__ ZB4,
    const float* __restrict__ lin_b,
    const float* __restrict__ w1, const float* __restrict__ b1v,
    const float* __restrict__ w2v,
    double* __restrict__ acc, double* __restrict__ lse) {
  __shared__ double rbuf[8];
  __shared__ double rbuf2[8];

  if (blockIdx.x < NB_INFO) {
    // ---------------- info phase: 8 lanes/edge, dual stream ----------------
    const int s8 = threadIdx.x & 7;
    float byr[16], wyr[16], w2r[16];
#pragma unroll
    for (int q = 0; q < 16; ++q) {
      int k = 16 * s8 + q;
      byr[q] = b1v[k];
      wyr[q] = w1[k * 131 + 130];
      w2r[q] = w2v[k];
    }
    const float byt0 = b1v[128], byt1 = b1v[129];
    const float wyt0 = w1[128 * 131 + 130], wyt1 = w1[129 * 131 + 130];
    const float w2t0 = w2v[128], w2t1 = w2v[129];
    int g = (blockIdx.x * 256 + threadIdx.x) >> 3;
    const int gs = (NB_INFO * 256) >> 3;
    float s1f = 0.f, lm = -INFINITY, lsum = 0.f;

    // stream A: edges [0, EHALF) (pos|neg); stream B: edges [EHALF, E3) (none2)
    int yAp_c = 0, yAs_c = 0, yBs_c = 0;
    uint4 PA_c = {}, QA_c = {}, PB_c = {}, QB_c = {};
    unsigned ptA_c = 0, qtA_c = 0, ptB_c = 0, qtB_c = 0;

#define FETCH_A(E, YPI, YSI, P4, Q4, PT_, QT_)                                          \
  {                                                                                     \
    int i, j;                                                                           \
    if ((E) < EPOS) { i = p0[E]; j = p1[E]; YPI = 0; }                                  \
    else { int t_ = (E) - EPOS; i = n0[t_]; j = n1[t_]; YPI = 1; }                      \
    int p_ = perm[E];                                                                   \
    YSI = (p_ < EPOS) ? 0 : ((p_ < EPOS + ENEG) ? 1 : 2);                               \
    P4 = *(const uint4*)(Pm + (size_t)i * 128 + 16 * s8);                               \
    Q4 = *(const uint4*)(Qm + (size_t)j * 128 + 16 * s8);                               \
    if (s8 == 0) { PT_ = PT[i]; QT_ = QT[j]; }                                          \
  }
#define FETCH_B(E, YSI, P4, Q4, PT_, QT_)                                               \
  {                                                                                     \
    int i = q0[E], j = q1[E];                                                           \
    int p_ = perm[(E) + EHALF];                                                         \
    YSI = (p_ < EPOS) ? 0 : ((p_ < EPOS + ENEG) ? 1 : 2);                               \
    P4 = *(const uint4*)(Pm + (size_t)i * 128 + 16 * s8);                               \
    Q4 = *(const uint4*)(Qm + (size_t)j * 128 + 16 * s8);                               \
    if (s8 == 0) { PT_ = PT[i]; QT_ = QT[j]; }                                          \
  }
#define INFO_COMPUTE(YPF, YSF, P4, Q4, PT_, QT_)                                        \
  {                                                                                     \
    float pv[16], qv[16];                                                               \
    de4(P4.x, pv); de4(P4.y, pv + 4); de4(P4.z, pv + 8); de4(P4.w, pv + 12);            \
    de4(Q4.x, qv); de4(Q4.y, qv + 4); de4(Q4.z, qv + 8); de4(Q4.w, qv + 12);            \
    float sp = 0.f, ss = 0.f;                                                           \
    _Pragma("unroll") for (int q = 0; q < 16; ++q) {                                    \
      float t_ = pv[q] + qv[q] + byr[q];                                                \
      sp = fmaf(fmaxf(fmaf(YPF, wyr[q], t_), 0.f), w2r[q], sp);                         \
      ss = fmaf(fmaxf(fmaf(YSF, wyr[q], t_), 0.f), w2r[q], ss);                         \
    }                                                                                   \
    if (s8 == 0) {                                                                      \
      float tp[4], tq[4];                                                               \
      de4(PT_, tp); de4(QT_, tq);                                                       \
      float t0 = tp[0] + tq[0] + byt0;                                                  \
      float t1 = tp[1] + tq[1] + byt1;                                                  \
      sp += fmaxf(fmaf(YPF, wyt0, t0), 0.f) * w2t0 + fmaxf(fmaf(YPF, wyt1, t1), 0.f) * w2t1; \
      ss += fmaxf(fmaf(YSF, wyt0, t0), 0.f) * w2t0 + fmaxf(fmaf(YSF, wyt1, t1), 0.f) * w2t1; \
    }                                                                                   \
    _Pragma("unroll") for (int m_ = 4; m_; m_ >>= 1) {                                  \
      sp += __shfl_xor(sp, m_, 64);                                                     \
      ss += __shfl_xor(ss, m_, 64);                                                     \
    }                                                                                   \
    if (s8 == 0) {                                                                      \
      s1f += sp;                                                                        \
      float nm = fmaxf(lm, ss);                                                         \
      lsum = lsum * __expf(lm - nm) + __expf(ss - nm);                                  \
      lm = nm;                                                                          \
    }                                                                                   \
  }

    int e = g;
    if (e < EHALF) {
      FETCH_A(e, yAp_c, yAs_c, PA_c, QA_c, ptA_c, qtA_c);
      FETCH_B(e, yBs_c, PB_c, QB_c, ptB_c, qtB_c);
    }
    while (e < EHALF) {
      int e2 = e + gs;
      int yAp_n = 0, yAs_n = 0, yBs_n = 0;
      uint4 PA_n = {}, QA_n = {}, PB_n = {}, QB_n = {};
      unsigned ptA_n = 0, qtA_n = 0, ptB_n = 0, qtB_n = 0;
      if (e2 < EHALF) {
        FETCH_A(e2, yAp_n, yAs_n, PA_n, QA_n, ptA_n, qtA_n);
        FETCH_B(e2, yBs_n, PB_n, QB_n, ptB_n, qtB_n);
      }
      INFO_COMPUTE((float)yAp_c, (float)yAs_c, PA_c, QA_c, ptA_c, qtA_c);
      INFO_COMPUTE(2.f, (float)yBs_c, PB_c, QB_c, ptB_c, qtB_c);
      e = e2;
      yAp_c = yAp_n; yAs_c = yAs_n; yBs_c = yBs_n;
      PA_c = PA_n; QA_c = QA_n; PB_c = PB_n; QB_c = QB_n;
      ptA_c = ptA_n; qtA_c = qtA_n; ptB_c = ptB_n; qtB_c = qtB_n;
    }
    breduce2((double)s1f, 0.0, acc + 3, acc + 6, rbuf);
    double lmd = (lsum > 0.f) ? (double)lm : -(double)INFINITY;
    lse_block_reduce(lmd, (double)lsum, lse + 2 * blockIdx.x, rbuf2);

  } else if (blockIdx.x < NB_INFO + NB_STRUCT) {
    // ---------------- struct phase: 8 lanes/edge, fp8 Y ----------------
    const int st = threadIdx.x & 7;
    int g = ((blockIdx.x - NB_INFO) * 256 + threadIdx.x) >> 3;
    const int gs = (NB_STRUCT * 256) >> 3;
    float s1f = 0.f, s2f = 0.f;

    bool pos_c = false;
    uint2 yi_c = {}, yj_c = {}, yk_c = {};
    float xi_c = 0.f, xj_c = 0.f, xk_c = 0.f;

#define ST_FETCH(E, POS, YI, YJ, YK, XI, XJ, XK)                       \
  {                                                                    \
    int i, j, kk;                                                      \
    POS = (E) < EPOS;                                                  \
    if (POS) { i = p0[E]; j = p1[E]; kk = pk[E]; }                     \
    else { int t = (E) - EPOS; i = n0[t]; j = n1[t]; kk = nk[t]; }     \
    YI = *(const uint2*)(YF8 + (size_t)i * 64 + 8 * st);               \
    YJ = *(const uint2*)(YF8 + (size_t)j * 64 + 8 * st);               \
    YK = *(const uint2*)(YF8 + (size_t)kk * 64 + 8 * st);              \
    if (st == 0) { XI = X0[i]; XJ = X0[j]; XK = X0[kk]; }              \
  }

    int e = g;
    if (e < EPOS + ENEG) ST_FETCH(e, pos_c, yi_c, yj_c, yk_c, xi_c, xj_c, xk_c);
    while (e < EPOS + ENEG) {
      int e2 = e + gs;
      bool pos_n = false;
      uint2 yi_n = {}, yj_n = {}, yk_n = {};
      float xi_n = 0.f, xj_n = 0.f, xk_n = 0.f;
      if (e2 < EPOS + ENEG) ST_FETCH(e2, pos_n, yi_n, yj_n, yk_n, xi_n, xj_n, xk_n);
      float ai[8], aj[8], ak[8];
      de4(yi_c.x, ai); de4(yi_c.y, ai + 4);
      de4(yj_c.x, aj); de4(yj_c.y, aj + 4);
      de4(yk_c.x, ak); de4(yk_c.y, ak + 4);
      float dij = 0.f, dik = 0.f;
#pragma unroll
      for (int q = 0; q < 8; ++q) {
        dij = fmaf(ai[q], aj[q], dij);
        dik = fmaf(ai[q], ak[q], dik);
      }
#pragma unroll
      for (int m = 4; m; m >>= 1) {
        dij += __shfl_xor(dij, m, 64);
        dik += __shfl_xor(dik, m, 64);
      }
      if (st == 0) {
        float sij = hsq(dij - xi_c * xj_c);
        float sik = hsq(dik - xi_c * xk_c);
        if (pos_c) s1f += fmaxf(sij - sik, 0.f);
        else s2f += fmaxf(sik - sij, 0.f);
      }
      e = e2;
      pos_c = pos_n; yi_c = yi_n; yj_c = yj_n; yk_c = yk_n;
      xi_c = xi_n; xj_c = xj_n; xk_c = xk_n;
    }
    breduce2((double)s1f, (double)s2f, acc + 1, acc + 2, rbuf);

  } else {
    // ---------------- nll phase: thread-per-edge ----------------
    const float c0 = lin_b[0], c1 = lin_b[1], c2 = lin_b[2];
    const float wp = 1.f / (3.f * EPOS), wn = 1.f / (3.f * ENEG), wo = 1.f / (3.f * ENON);
    double s = 0.0;
    int t0 = (blockIdx.x - NB_INFO - NB_STRUCT) * 256 + threadIdx.x;
    for (int e = t0; e < E3; e += NB_NLL * 256) {
      int i, j, tgt;
      float wgt;
      if (e < EPOS) { i = p0[e]; j = p1[e]; tgt = 0; wgt = wp; }
      else if (e < EPOS + ENEG) { int t = e - EPOS; i = n0[t]; j = n1[t]; tgt = 1; wgt = wn; }
      else { int t = e - EPOS - ENEG; i = o0[t]; j = o1[t]; tgt = 2; wgt = wo; }
      float4 a = ZA4[i], b = ZB4[j];
      float l0 = a.x + b.x + c0, l1 = a.y + b.y + c1, l2 = a.z + b.z + c2;
      float mx = fmaxf(l0, fmaxf(l1, l2));
      float lsev = mx + __logf(__expf(l0 - mx) + __expf(l1 - mx) + __expf(l2 - mx));
      float lt = (tgt == 0) ? l0 : ((tgt == 1) ? l1 : l2);
      s += (double)((lsev - lt) * wgt);
    }
    breduce2(s, 0.0, acc + 0, acc + 5, rbuf);
  }
}

__global__ void k_final(const double* __restrict__ acc, const double* __restrict__ lse,
                        float* __restrict__ out) {
  __shared__ double rb[8];
  double lm = -INFINITY, ls = 0.0;
  for (int i = threadIdx.x; i < NLSE; i += blockDim.x)
    lse_combine(lm, ls, lse[2 * i], lse[2 * i + 1]);
#pragma unroll
  for (int d = 32; d; d >>= 1) {
    double om = __shfl_xor(lm, d, 64);
    double os = __shfl_xor(ls, d, 64);
    lse_combine(lm, ls, om, os);
  }
  int l = threadIdx.x & 63, w = threadIdx.x >> 6;
  if (l == 0) { rb[2 * w] = lm; rb[2 * w + 1] = ls; }
  __syncthreads();
  if (threadIdx.x == 0) {
    double M = rb[0], S = rb[1];
    int nw = blockDim.x >> 6;
    for (int i = 1; i < nw; ++i) lse_combine(M, S, rb[2 * i], rb[2 * i + 1]);
    // b2 cancels between mean(pred) and logmeanexp(shuffle); omitted in both.
    double logmean = M + log(S) - log((double)E3);
    double nll = acc[0];
    double l1 = acc[1] / (double)EPOS;
    double l2 = acc[2] / (double)ENEG;
    double s1m = acc[3] / (double)E3;
    double l3 = -(s1m - logmean);
    out[0] = (float)(nll + 5.0 * (l1 + l2) + 0.1 * l3);
  }
}

extern "C" void kernel_launch(void* const* d_in, const int* in_sizes, int n_in,
                              void* d_out, int out_size, void* d_ws, size_t ws_size,
                              hipStream_t stream) {
  const float* z     = (const float*)d_in[0];
  const float* lin_w = (const float*)d_in[1];
  const float* lin_b = (const float*)d_in[2];
  const float* w1    = (const float*)d_in[3];
  const float* b1v   = (const float*)d_in[4];
  const float* w2v   = (const float*)d_in[5];
  const int* pos  = (const int*)d_in[7];
  const int* neg  = (const int*)d_in[8];
  const int* non  = (const int*)d_in[9];
  const int* non2 = (const int*)d_in[10];
  const int* posk = (const int*)d_in[11];
  const int* negk = (const int*)d_in[12];
  const int* perm = (const int*)d_in[13];

  char* ws = (char*)d_ws;
  double* acc = (double*)(ws + ACC_OFF);
  double* lse = (double*)(ws + LSE_OFF);
  float* X0   = (float*)(ws + X0_OFF);
  float4* ZA4 = (float4*)(ws + ZA_OFF);
  float4* ZB4 = (float4*)(ws + ZB_OFF);
  unsigned short* WT  = (unsigned short*)(ws + WT_OFF);
  unsigned char* YF8  = (unsigned char*)(ws + YF8_OFF);
  unsigned char* PTb  = (unsigned char*)(ws + PT_OFF);
  unsigned char* QTb  = (unsigned char*)(ws + QT_OFF);
  unsigned char* PM   = (unsigned char*)(ws + PM_OFF);
  unsigned char* QM   = (unsigned char*)(ws + QM_OFF);

  hipLaunchKernelGGL(k_init, dim3(17), dim3(256), 0, stream, w1, acc, lse, WT);
  hipLaunchKernelGGL(k_pre, dim3((NN + 127) / 128), dim3(128), 0, stream,
                     z, lin_w, WT, X0, YF8, ZA4, ZB4, PM, QM, PTb, QTb);
  hipLaunchKernelGGL(k_edges, dim3(NB_EDGES), dim3(256), 0, stream,
                     pos, pos + EPOS, neg, neg + ENEG, non, non + ENON,
                     non2, non2 + ENON, posk, negk, perm,
                     PM, QM, (const unsigned short*)PTb, (const unsigned short*)QTb,
                     YF8, X0, ZA4, ZB4, lin_b, w1, b1v, w2v, acc, lse);
  hipLaunchKernelGGL(k_final, dim3(1), dim3(256), 0, stream, acc, lse, (float*)d_out);
}

// Round 7
// 274.330 us; speedup vs baseline: 1.0229x; 1.0229x over previous
//
#include <hip/hip_runtime.h>
#include <hip/hip_fp16.h>
#include <math.h>

// Problem constants
#define NN    100000
#define EPOS  250000
#define ENEG  250000
#define ENON  500000
#define E3   1000000
#define EHALF 500000
#define NLSE  4096

// k_edges phase split
#define NB_INFO   2816
#define NB_STRUCT 960
#define NB_NLL    320
#define NB_EDGES  (NB_INFO + NB_STRUCT + NB_NLL)

// Workspace layout (bytes, 16B-aligned sections)
#define ACC_OFF 0
#define LSE_OFF 256          // 65,536 -> 65,792
#define X0_OFF  66048        // 400,000 -> 466,048
#define ZA_OFF  466176       // 1.6M -> 2,066,176
#define ZB_OFF  2066176      // 1.6M -> 3,666,176
#define WT_OFF  3666176      // 272x104 bf16 = 56,576 -> 3,722,752
#define YF8_OFF 3722752      // 100k x 64 fp8 = 6.4M -> 10,122,752
#define PT_OFF  10122752     // 200,000 -> 10,322,752
#define QT_OFF  10322752     // 200,000 -> 10,522,752
#define PM_OFF  10522752     // 12.8M -> 23,322,752
#define QM_OFF  23322752     // 12.8M -> 36,122,752  (~36.2 MB total)

typedef __attribute__((ext_vector_type(8))) short bh8;
typedef __attribute__((ext_vector_type(4))) float f32x4;
typedef __attribute__((ext_vector_type(2))) float f32x2;

// acc slots: 0=nll, 1=l1_sum, 2=l2_sum, 3=s1(pred sum), 5/6 dummies

__device__ __forceinline__ unsigned short f2bf(float f) {
  unsigned u = __float_as_uint(f);
  unsigned r = (u + 0x7FFFu + ((u >> 16) & 1u)) >> 16;
  return (unsigned short)r;
}

#if __has_builtin(__builtin_amdgcn_cvt_pk_f32_bf8) && __has_builtin(__builtin_amdgcn_cvt_pk_bf8_f32)
#define HAVE_BF8 1
#endif

// Decode 4 packed bf8 (e5m2) bytes -> 4 floats.
__device__ __forceinline__ void de4(unsigned v, float* o) {
#ifdef HAVE_BF8
  f32x2 lo = __builtin_amdgcn_cvt_pk_f32_bf8((int)v, false);
  f32x2 hi = __builtin_amdgcn_cvt_pk_f32_bf8((int)v, true);
  o[0] = lo[0]; o[1] = lo[1]; o[2] = hi[0]; o[3] = hi[1];
#else
  o[0] = __half2float(__ushort_as_half((unsigned short)((v & 0xFFu) << 8)));
  o[1] = __half2float(__ushort_as_half((unsigned short)(((v >> 8) & 0xFFu) << 8)));
  o[2] = __half2float(__ushort_as_half((unsigned short)(((v >> 16) & 0xFFu) << 8)));
  o[3] = __half2float(__ushort_as_half((unsigned short)((v >> 24) << 8)));
#endif
}

// Encode 2 floats -> 2 bf8 bytes (low 16 bits), clamped to finite e5m2 range.
__device__ __forceinline__ unsigned pk2(float a, float b) {
  a = fminf(fmaxf(a, -57344.f), 57344.f);
  b = fminf(fmaxf(b, -57344.f), 57344.f);
#ifdef HAVE_BF8
  return (unsigned)__builtin_amdgcn_cvt_pk_bf8_f32(a, b, 0, false) & 0xFFFFu;
#else
  unsigned short ha = __half_as_ushort(__float2half(a));
  unsigned short hb = __half_as_ushort(__float2half(b));
  ha = (unsigned short)((ha + 0x7Fu + ((ha >> 8) & 1u)) >> 8);
  hb = (unsigned short)((hb + 0x7Fu + ((hb >> 8) & 1u)) >> 8);
  return (unsigned)ha | ((unsigned)hb << 8);
#endif
}

__device__ __forceinline__ void breduce2(double v0, double v1, double* g0, double* g1,
                                         double* rbuf) {
#pragma unroll
  for (int m = 32; m; m >>= 1) {
    v0 += __shfl_xor(v0, m, 64);
    v1 += __shfl_xor(v1, m, 64);
  }
  int l = threadIdx.x & 63, w = threadIdx.x >> 6;
  if (l == 0) { rbuf[2 * w] = v0; rbuf[2 * w + 1] = v1; }
  __syncthreads();
  if (threadIdx.x == 0) {
    int nw = blockDim.x >> 6;
    double s0 = 0.0, s1 = 0.0;
    for (int i = 0; i < nw; ++i) { s0 += rbuf[2 * i]; s1 += rbuf[2 * i + 1]; }
    atomicAdd(g0, s0);
    atomicAdd(g1, s1);
  }
}

__device__ __forceinline__ void lse_combine(double& m, double& s, double om, double os) {
  double M = fmax(m, om);
  double sn = 0.0;
  if (m > -INFINITY) sn += s * exp(m - M);
  if (om > -INFINITY) sn += os * exp(om - M);
  m = M;
  s = sn;
}

__device__ __forceinline__ void lse_block_reduce(double lm, double ls, double* out_pair,
                                                 double* rbuf) {
#pragma unroll
  for (int d = 32; d; d >>= 1) {
    double om = __shfl_xor(lm, d, 64);
    double os = __shfl_xor(ls, d, 64);
    lse_combine(lm, ls, om, os);
  }
  __syncthreads();
  int l = threadIdx.x & 63, w = threadIdx.x >> 6;
  if (l == 0) { rbuf[2 * w] = lm; rbuf[2 * w + 1] = ls; }
  __syncthreads();
  if (threadIdx.x == 0) {
    int nw = blockDim.x >> 6;
    double M = rbuf[0], S = rbuf[1];
    for (int i = 1; i < nw; ++i) lse_combine(M, S, rbuf[2 * i], rbuf[2 * i + 1]);
    out_pair[0] = M;
    out_pair[1] = S;
  }
}

// k_init: zero acc + lse pairs; build Wt_g [272 cols][104 k] bf16 (W-ext transposed).
// col c<130 -> P row c of w1; 136<=c<266 -> Q row (c-136); k<64 y coeff, k==64 x0 coeff.
__global__ __launch_bounds__(256) void k_init(const float* __restrict__ w1,
                                              double* __restrict__ acc,
                                              double* __restrict__ lse,
                                              unsigned short* __restrict__ wt) {
  int gid = blockIdx.x * 256 + threadIdx.x;
  if (gid < NLSE) { lse[2 * gid] = -INFINITY; lse[2 * gid + 1] = 0.0; }
  if (gid < 8) acc[gid] = 0.0;
  for (int u = threadIdx.x; u < 16 * 104; u += 256) {
    int c = 16 * blockIdx.x + u / 104;
    int k = u % 104;
    float val = 0.f;
    if (c < 130) {
      if (k < 64) val = w1[c * 131 + 1 + k];
      else if (k == 64) val = w1[c * 131];
    } else if (c >= 136 && c < 266) {
      int r = c - 136;
      if (k < 64) val = w1[r * 131 + 66 + k];
      else if (k == 64) val = w1[r * 131 + 65];
    }
    wt[(size_t)c * 104 + k] = f2bf(val);
  }
}

// k_pre: fused per-node precompute + PQ GEMM.
// Phase 1: thread-per-node y/x0/folds, y -> LDS bf16 + YF8.
// Phase 2: per wave, per 16-node tile: MFMA(A=W,B=Y) -> fp8 tile staged in per-wave
// LDS buffer (row stride 304B). Phase 3: coalesced full-line uint4 copy-out
// (8 nodes x 128B = 1KB contiguous per instruction per table).
__global__ __launch_bounds__(128) void k_pre(
    const float* __restrict__ z, const float* __restrict__ lin_w,
    const unsigned short* __restrict__ wt,
    float* __restrict__ X0, unsigned char* __restrict__ YF8,
    float4* __restrict__ ZA4, float4* __restrict__ ZB4,
    unsigned char* __restrict__ Pm, unsigned char* __restrict__ Qm,
    unsigned char* __restrict__ PTb, unsigned char* __restrict__ QTb) {
  __shared__ float WL[384];
  __shared__ __align__(16) unsigned short YL[128 * 96];      // 24,576 B
  __shared__ __align__(16) unsigned char SB[2][16 * 304];    // 9,728 B per-wave staging
  for (int u = threadIdx.x; u < 384; u += 128) {
    int rr = u >> 6, d = u & 63;
    WL[u] = (rr < 3) ? lin_w[rr * 128 + d] : lin_w[(rr - 3) * 128 + 64 + d];
  }
  __syncthreads();
  const int base = blockIdx.x * 128;
  const int n = base + threadIdx.x;
  if (n < NN) {
    const float4* zr = (const float4*)(z + (size_t)n * 64);
    const float4* wl4 = (const float4*)WL;
    float4 zc[16];
    float zn2 = 0.f, d0 = 0.f, d1 = 0.f, d2 = 0.f, d3 = 0.f, d4 = 0.f, d5 = 0.f;
#pragma unroll
    for (int c = 0; c < 16; ++c) {
      float4 v = zr[c];
      zc[c] = v;
      zn2 += v.x * v.x + v.y * v.y + v.z * v.z + v.w * v.w;
      float4 w0 = wl4[c];
      float4 w1r = wl4[16 + c];
      float4 w2r = wl4[32 + c];
      float4 w3 = wl4[48 + c];
      float4 w4 = wl4[64 + c];
      float4 w5 = wl4[80 + c];
      d0 += v.x * w0.x + v.y * w0.y + v.z * w0.z + v.w * w0.w;
      d1 += v.x * w1r.x + v.y * w1r.y + v.z * w1r.z + v.w * w1r.w;
      d2 += v.x * w2r.x + v.y * w2r.y + v.z * w2r.z + v.w * w2r.w;
      d3 += v.x * w3.x + v.y * w3.y + v.z * w3.z + v.w * w3.w;
      d4 += v.x * w4.x + v.y * w4.y + v.z * w4.z + v.w * w4.w;
      d5 += v.x * w5.x + v.y * w5.y + v.z * w5.z + v.w * w5.w;
    }
    float zn = fmaxf(sqrtf(zn2), 1e-15f);
    float t = 1.7320508075688772f * zn;
    float e = __expf(t);
    float sh = 0.5f * (e - __frcp_rn(e));
    float fac = (t < 1e-4f) ? (1.f + t * t * 0.16666667f) : (sh / t);
    float yn2 = fac * fac * zn2;
    float x0 = sqrtf(0.33333333333333333f + yn2);
    X0[n] = x0;
    ZA4[n] = make_float4(d0, d1, d2, 0.f);
    ZB4[n] = make_float4(d3, d4, d5, 0.f);
    unsigned short* yrow = YL + threadIdx.x * 96;
    unsigned yu[16];
#pragma unroll
    for (int c = 0; c < 16; ++c) {
      float4 v = zc[c];
      ushort4 o;
      o.x = f2bf(fac * v.x); o.y = f2bf(fac * v.y);
      o.z = f2bf(fac * v.z); o.w = f2bf(fac * v.w);
      *(ushort4*)(yrow + 4 * c) = o;
      yu[c] = pk2(fac * v.x, fac * v.y) | (pk2(fac * v.z, fac * v.w) << 16);
    }
    ushort4 xx; xx.x = f2bf(x0); xx.y = 0; xx.z = 0; xx.w = 0;
    *(ushort4*)(yrow + 64) = xx;
    ushort4 zz; zz.x = 0; zz.y = 0; zz.z = 0; zz.w = 0;
#pragma unroll
    for (int c = 17; c < 24; ++c) *(ushort4*)(yrow + 4 * c) = zz;
    uint4* y8 = (uint4*)(YF8 + (size_t)n * 64);
    y8[0] = make_uint4(yu[0], yu[1], yu[2], yu[3]);
    y8[1] = make_uint4(yu[4], yu[5], yu[6], yu[7]);
    y8[2] = make_uint4(yu[8], yu[9], yu[10], yu[11]);
    y8[3] = make_uint4(yu[12], yu[13], yu[14], yu[15]);
  }
  __syncthreads();
  // ---- phase 2+3: GEMM into LDS staging, then coalesced copy-out ----
  const int l = threadIdx.x & 63;
  const int w = threadIdx.x >> 6;
  const int col = l & 15, kq = l >> 4;
  unsigned char* sb = SB[w];
  const int ntiles = min(8, (NN - base) >> 4);
  for (int t = w; t < ntiles; t += 2) {
    const unsigned short* yr = YL + (t * 16 + col) * 96 + kq * 8;
    bh8 y0 = *(const bh8*)(yr);
    bh8 y1 = *(const bh8*)(yr + 32);
    bh8 y2 = *(const bh8*)(yr + 64);
#pragma unroll
    for (int nt = 0; nt < 17; ++nt) {
      const unsigned short* wr = wt + (size_t)(nt * 16 + col) * 104 + kq * 8;
      bh8 b0 = *(const bh8*)(wr);
      bh8 b1 = *(const bh8*)(wr + 32);
      bh8 b2 = *(const bh8*)(wr + 64);
      f32x4 a4 = {0.f, 0.f, 0.f, 0.f};
      a4 = __builtin_amdgcn_mfma_f32_16x16x32_bf16(b0, y0, a4, 0, 0, 0);
      a4 = __builtin_amdgcn_mfma_f32_16x16x32_bf16(b1, y1, a4, 0, 0, 0);
      a4 = __builtin_amdgcn_mfma_f32_16x16x32_bf16(b2, y2, a4, 0, 0, 0);
      // lane holds outs ob..ob+3 (ob = nt*16 + kq*4) for node = col of this tile
      int ob = nt * 16 + kq * 4;
      unsigned u = pk2(a4[0], a4[1]) | (pk2(a4[2], a4[3]) << 16);
      unsigned char* row = sb + col * 304;
      if (nt < 8) {
        *(unsigned*)(row + ob) = u;                               // P k=0..127
      } else if (nt == 8) {
        if (kq == 0) *(unsigned short*)(row + 256) = (unsigned short)(u & 0xFFFFu);  // P tails
        else if (kq >= 2) *(unsigned*)(row + 128 + (ob - 136)) = u;  // Q k=0..7
      } else if (nt < 16) {
        *(unsigned*)(row + 128 + (ob - 136)) = u;                 // Q k=8..119
      } else {
        if (kq < 2) *(unsigned*)(row + 128 + (ob - 136)) = u;     // Q k=120..127
        else if (kq == 2) *(unsigned short*)(row + 258) = (unsigned short)(u & 0xFFFFu);  // Q tails
      }
    }
    // copy-out (wave-local buffer; compiler orders LDS write->read within wave)
    const size_t gb = (size_t)(base + t * 16);
#pragma unroll
    for (int r = 0; r < 2; ++r) {
      int idx = r * 64 + l;              // 0..127
      int node = idx >> 3, part = idx & 7;
      uint4 vp = *(const uint4*)(sb + node * 304 + part * 16);
      *(uint4*)(Pm + (gb + node) * 128 + part * 16) = vp;
      uint4 vq = *(const uint4*)(sb + node * 304 + 128 + part * 16);
      *(uint4*)(Qm + (gb + node) * 128 + part * 16) = vq;
    }
    if (l < 16) {
      *(unsigned short*)(PTb + (gb + l) * 2) = *(const unsigned short*)(sb + l * 304 + 256);
      *(unsigned short*)(QTb + (gb + l) * 2) = *(const unsigned short*)(sb + l * 304 + 258);
    }
  }
}

__device__ __forceinline__ float hsq(float mdot) {
  float th = fmaxf(-3.f * mdot, 1.f + 1e-7f);
  float ach = __logf(th + sqrtf(th * th - 1.f));
  return fminf(ach * ach * (1.f / 3.f), 50.f);
}

// k_edges: fused nll + struct + info, phase by block range.
__global__ __launch_bounds__(256) void k_edges(
    const int* __restrict__ p0, const int* __restrict__ p1,
    const int* __restrict__ n0, const int* __restrict__ n1,
    const int* __restrict__ o0, const int* __restrict__ o1,   // none (nll)
    const int* __restrict__ q0, const int* __restrict__ q1,   // none2 (info)
    const int* __restrict__ pk, const int* __restrict__ nk,
    const int* __restrict__ perm,
    const unsigned char* __restrict__ Pm, const unsigned char* __restrict__ Qm,
    const unsigned short* __restrict__ PT, const unsigned short* __restrict__ QT,
    const unsigned char* __restrict__ YF8, const float* __restrict__ X0,
    const float4* __restrict__ ZA4, const float4* __restrict__ ZB4,
    const float* __restrict__ lin_b,
    const float* __restrict__ w1, const float* __restrict__ b1v,
    const float* __restrict__ w2v,
    double* __restrict__ acc, double* __restrict__ lse) {
  __shared__ double rbuf[8];
  __shared__ double rbuf2[8];

  if (blockIdx.x < NB_INFO) {
    // ---------------- info phase: 8 lanes/edge, dual stream ----------------
    const int s8 = threadIdx.x & 7;
    float byr[16], wyr[16], w2r[16];
#pragma unroll
    for (int q = 0; q < 16; ++q) {
      int k = 16 * s8 + q;
      byr[q] = b1v[k];
      wyr[q] = w1[k * 131 + 130];
      w2r[q] = w2v[k];
    }
    const float byt0 = b1v[128], byt1 = b1v[129];
    const float wyt0 = w1[128 * 131 + 130], wyt1 = w1[129 * 131 + 130];
    const float w2t0 = w2v[128], w2t1 = w2v[129];
    int g = (blockIdx.x * 256 + threadIdx.x) >> 3;
    const int gs = (NB_INFO * 256) >> 3;
    float s1f = 0.f, lm = -INFINITY, lsum = 0.f;

    // stream A: edges [0, EHALF) (pos|neg); stream B: edges [EHALF, E3) (none2)
    int yAp_c = 0, yAs_c = 0, yBs_c = 0;
    uint4 PA_c = {}, QA_c = {}, PB_c = {}, QB_c = {};
    unsigned ptA_c = 0, qtA_c = 0, ptB_c = 0, qtB_c = 0;

#define FETCH_A(E, YPI, YSI, P4, Q4, PT_, QT_)                                          \
  {                                                                                     \
    int i, j;                                                                           \
    if ((E) < EPOS) { i = p0[E]; j = p1[E]; YPI = 0; }                                  \
    else { int t_ = (E) - EPOS; i = n0[t_]; j = n1[t_]; YPI = 1; }                      \
    int p_ = perm[E];                                                                   \
    YSI = (p_ < EPOS) ? 0 : ((p_ < EPOS + ENEG) ? 1 : 2);                               \
    P4 = *(const uint4*)(Pm + (size_t)i * 128 + 16 * s8);                               \
    Q4 = *(const uint4*)(Qm + (size_t)j * 128 + 16 * s8);                               \
    if (s8 == 0) { PT_ = PT[i]; QT_ = QT[j]; }                                          \
  }
#define FETCH_B(E, YSI, P4, Q4, PT_, QT_)                                               \
  {                                                                                     \
    int i = q0[E], j = q1[E];                                                           \
    int p_ = perm[(E) + EHALF];                                                         \
    YSI = (p_ < EPOS) ? 0 : ((p_ < EPOS + ENEG) ? 1 : 2);                               \
    P4 = *(const uint4*)(Pm + (size_t)i * 128 + 16 * s8);                               \
    Q4 = *(const uint4*)(Qm + (size_t)j * 128 + 16 * s8);                               \
    if (s8 == 0) { PT_ = PT[i]; QT_ = QT[j]; }                                          \
  }
#define INFO_COMPUTE(YPF, YSF, P4, Q4, PT_, QT_)                                        \
  {                                                                                     \
    float pv[16], qv[16];                                                               \
    de4(P4.x, pv); de4(P4.y, pv + 4); de4(P4.z, pv + 8); de4(P4.w, pv + 12);            \
    de4(Q4.x, qv); de4(Q4.y, qv + 4); de4(Q4.z, qv + 8); de4(Q4.w, qv + 12);            \
    float sp = 0.f, ss = 0.f;                                                           \
    _Pragma("unroll") for (int q = 0; q < 16; ++q) {                                    \
      float t_ = pv[q] + qv[q] + byr[q];                                                \
      sp = fmaf(fmaxf(fmaf(YPF, wyr[q], t_), 0.f), w2r[q], sp);                         \
      ss = fmaf(fmaxf(fmaf(YSF, wyr[q], t_), 0.f), w2r[q], ss);                         \
    }                                                                                   \
    if (s8 == 0) {                                                                      \
      float tp[4], tq[4];                                                               \
      de4(PT_, tp); de4(QT_, tq);                                                       \
      float t0 = tp[0] + tq[0] + byt0;                                                  \
      float t1 = tp[1] + tq[1] + byt1;                                                  \
      sp += fmaxf(fmaf(YPF, wyt0, t0), 0.f) * w2t0 + fmaxf(fmaf(YPF, wyt1, t1), 0.f) * w2t1; \
      ss += fmaxf(fmaf(YSF, wyt0, t0), 0.f) * w2t0 + fmaxf(fmaf(YSF, wyt1, t1), 0.f) * w2t1; \
    }                                                                                   \
    _Pragma("unroll") for (int m_ = 4; m_; m_ >>= 1) {                                  \
      sp += __shfl_xor(sp, m_, 64);                                                     \
      ss += __shfl_xor(ss, m_, 64);                                                     \
    }                                                                                   \
    if (s8 == 0) {                                                                      \
      s1f += sp;                                                                        \
      float nm = fmaxf(lm, ss);                                                         \
      lsum = lsum * __expf(lm - nm) + __expf(ss - nm);                                  \
      lm = nm;                                                                          \
    }                                                                                   \
  }

    int e = g;
    if (e < EHALF) {
      FETCH_A(e, yAp_c, yAs_c, PA_c, QA_c, ptA_c, qtA_c);
      FETCH_B(e, yBs_c, PB_c, QB_c, ptB_c, qtB_c);
    }
    while (e < EHALF) {
      int e2 = e + gs;
      int yAp_n = 0, yAs_n = 0, yBs_n = 0;
      uint4 PA_n = {}, QA_n = {}, PB_n = {}, QB_n = {};
      unsigned ptA_n = 0, qtA_n = 0, ptB_n = 0, qtB_n = 0;
      if (e2 < EHALF) {
        FETCH_A(e2, yAp_n, yAs_n, PA_n, QA_n, ptA_n, qtA_n);
        FETCH_B(e2, yBs_n, PB_n, QB_n, ptB_n, qtB_n);
      }
      INFO_COMPUTE((float)yAp_c, (float)yAs_c, PA_c, QA_c, ptA_c, qtA_c);
      INFO_COMPUTE(2.f, (float)yBs_c, PB_c, QB_c, ptB_c, qtB_c);
      e = e2;
      yAp_c = yAp_n; yAs_c = yAs_n; yBs_c = yBs_n;
      PA_c = PA_n; QA_c = QA_n; PB_c = PB_n; QB_c = QB_n;
      ptA_c = ptA_n; qtA_c = qtA_n; ptB_c = ptB_n; qtB_c = qtB_n;
    }
    breduce2((double)s1f, 0.0, acc + 3, acc + 6, rbuf);
    double lmd = (lsum > 0.f) ? (double)lm : -(double)INFINITY;
    lse_block_reduce(lmd, (double)lsum, lse + 2 * blockIdx.x, rbuf2);

  } else if (blockIdx.x < NB_INFO + NB_STRUCT) {
    // ---------------- struct phase: 8 lanes/edge, fp8 Y ----------------
    const int st = threadIdx.x & 7;
    int g = ((blockIdx.x - NB_INFO) * 256 + threadIdx.x) >> 3;
    const int gs = (NB_STRUCT * 256) >> 3;
    float s1f = 0.f, s2f = 0.f;

    bool pos_c = false;
    uint2 yi_c = {}, yj_c = {}, yk_c = {};
    float xi_c = 0.f, xj_c = 0.f, xk_c = 0.f;

#define ST_FETCH(E, POS, YI, YJ, YK, XI, XJ, XK)                       \
  {                                                                    \
    int i, j, kk;                                                      \
    POS = (E) < EPOS;                                                  \
    if (POS) { i = p0[E]; j = p1[E]; kk = pk[E]; }                     \
    else { int t = (E) - EPOS; i = n0[t]; j = n1[t]; kk = nk[t]; }     \
    YI = *(const uint2*)(YF8 + (size_t)i * 64 + 8 * st);               \
    YJ = *(const uint2*)(YF8 + (size_t)j * 64 + 8 * st);               \
    YK = *(const uint2*)(YF8 + (size_t)kk * 64 + 8 * st);              \
    if (st == 0) { XI = X0[i]; XJ = X0[j]; XK = X0[kk]; }              \
  }

    int e = g;
    if (e < EPOS + ENEG) ST_FETCH(e, pos_c, yi_c, yj_c, yk_c, xi_c, xj_c, xk_c);
    while (e < EPOS + ENEG) {
      int e2 = e + gs;
      bool pos_n = false;
      uint2 yi_n = {}, yj_n = {}, yk_n = {};
      float xi_n = 0.f, xj_n = 0.f, xk_n = 0.f;
      if (e2 < EPOS + ENEG) ST_FETCH(e2, pos_n, yi_n, yj_n, yk_n, xi_n, xj_n, xk_n);
      float ai[8], aj[8], ak[8];
      de4(yi_c.x, ai); de4(yi_c.y, ai + 4);
      de4(yj_c.x, aj); de4(yj_c.y, aj + 4);
      de4(yk_c.x, ak); de4(yk_c.y, ak + 4);
      float dij = 0.f, dik = 0.f;
#pragma unroll
      for (int q = 0; q < 8; ++q) {
        dij = fmaf(ai[q], aj[q], dij);
        dik = fmaf(ai[q], ak[q], dik);
      }
#pragma unroll
      for (int m = 4; m; m >>= 1) {
        dij += __shfl_xor(dij, m, 64);
        dik += __shfl_xor(dik, m, 64);
      }
      if (st == 0) {
        float sij = hsq(dij - xi_c * xj_c);
        float sik = hsq(dik - xi_c * xk_c);
        if (pos_c) s1f += fmaxf(sij - sik, 0.f);
        else s2f += fmaxf(sik - sij, 0.f);
      }
      e = e2;
      pos_c = pos_n; yi_c = yi_n; yj_c = yj_n; yk_c = yk_n;
      xi_c = xi_n; xj_c = xj_n; xk_c = xk_n;
    }
    breduce2((double)s1f, (double)s2f, acc + 1, acc + 2, rbuf);

  } else {
    // ---------------- nll phase: thread-per-edge ----------------
    const float c0 = lin_b[0], c1 = lin_b[1], c2 = lin_b[2];
    const float wp = 1.f / (3.f * EPOS), wn = 1.f / (3.f * ENEG), wo = 1.f / (3.f * ENON);
    double s = 0.0;
    int t0 = (blockIdx.x - NB_INFO - NB_STRUCT) * 256 + threadIdx.x;
    for (int e = t0; e < E3; e += NB_NLL * 256) {
      int i, j, tgt;
      float wgt;
      if (e < EPOS) { i = p0[e]; j = p1[e]; tgt = 0; wgt = wp; }
      else if (e < EPOS + ENEG) { int t = e - EPOS; i = n0[t]; j = n1[t]; tgt = 1; wgt = wn; }
      else { int t = e - EPOS - ENEG; i = o0[t]; j = o1[t]; tgt = 2; wgt = wo; }
      float4 a = ZA4[i], b = ZB4[j];
      float l0 = a.x + b.x + c0, l1 = a.y + b.y + c1, l2 = a.z + b.z + c2;
      float mx = fmaxf(l0, fmaxf(l1, l2));
      float lsev = mx + __logf(__expf(l0 - mx) + __expf(l1 - mx) + __expf(l2 - mx));
      float lt = (tgt == 0) ? l0 : ((tgt == 1) ? l1 : l2);
      s += (double)((lsev - lt) * wgt);
    }
    breduce2(s, 0.0, acc + 0, acc + 5, rbuf);
  }
}

__global__ void k_final(const double* __restrict__ acc, const double* __restrict__ lse,
                        float* __restrict__ out) {
  __shared__ double rb[8];
  double lm = -INFINITY, ls = 0.0;
  for (int i = threadIdx.x; i < NLSE; i += blockDim.x)
    lse_combine(lm, ls, lse[2 * i], lse[2 * i + 1]);
#pragma unroll
  for (int d = 32; d; d >>= 1) {
    double om = __shfl_xor(lm, d, 64);
    double os = __shfl_xor(ls, d, 64);
    lse_combine(lm, ls, om, os);
  }
  int l = threadIdx.x & 63, w = threadIdx.x >> 6;
  if (l == 0) { rb[2 * w] = lm; rb[2 * w + 1] = ls; }
  __syncthreads();
  if (threadIdx.x == 0) {
    double M = rb[0], S = rb[1];
    int nw = blockDim.x >> 6;
    for (int i = 1; i < nw; ++i) lse_combine(M, S, rb[2 * i], rb[2 * i + 1]);
    // b2 cancels between mean(pred) and logmeanexp(shuffle); omitted in both.
    double logmean = M + log(S) - log((double)E3);
    double nll = acc[0];
    double l1 = acc[1] / (double)EPOS;
    double l2 = acc[2] / (double)ENEG;
    double s1m = acc[3] / (double)E3;
    double l3 = -(s1m - logmean);
    out[0] = (float)(nll + 5.0 * (l1 + l2) + 0.1 * l3);
  }
}

extern "C" void kernel_launch(void* const* d_in, const int* in_sizes, int n_in,
                              void* d_out, int out_size, void* d_ws, size_t ws_size,
                              hipStream_t stream) {
  const float* z     = (const float*)d_in[0];
  const float* lin_w = (const float*)d_in[1];
  const float* lin_b = (const float*)d_in[2];
  const float* w1    = (const float*)d_in[3];
  const float* b1v   = (const float*)d_in[4];
  const float* w2v   = (const float*)d_in[5];
  const int* pos  = (const int*)d_in[7];
  const int* neg  = (const int*)d_in[8];
  const int* non  = (const int*)d_in[9];
  const int* non2 = (const int*)d_in[10];
  const int* posk = (const int*)d_in[11];
  const int* negk = (const int*)d_in[12];
  const int* perm = (const int*)d_in[13];

  char* ws = (char*)d_ws;
  double* acc = (double*)(ws + ACC_OFF);
  double* lse = (double*)(ws + LSE_OFF);
  float* X0   = (float*)(ws + X0_OFF);
  float4* ZA4 = (float4*)(ws + ZA_OFF);
  float4* ZB4 = (float4*)(ws + ZB_OFF);
  unsigned short* WT  = (unsigned short*)(ws + WT_OFF);
  unsigned char* YF8  = (unsigned char*)(ws + YF8_OFF);
  unsigned char* PTb  = (unsigned char*)(ws + PT_OFF);
  unsigned char* QTb  = (unsigned char*)(ws + QT_OFF);
  unsigned char* PM   = (unsigned char*)(ws + PM_OFF);
  unsigned char* QM   = (unsigned char*)(ws + QM_OFF);

  hipLaunchKernelGGL(k_init, dim3(17), dim3(256), 0, stream, w1, acc, lse, WT);
  hipLaunchKernelGGL(k_pre, dim3((NN + 127) / 128), dim3(128), 0, stream,
                     z, lin_w, WT, X0, YF8, ZA4, ZB4, PM, QM, PTb, QTb);
  hipLaunchKernelGGL(k_edges, dim3(NB_EDGES), dim3(256), 0, stream,
                     pos, pos + EPOS, neg, neg + ENEG, non, non + ENON,
                     non2, non2 + ENON, posk, negk, perm,
                     PM, QM, (const unsigned short*)PTb, (const unsigned short*)QTb,
                     YF8, X0, ZA4, ZB4, lin_b, w1, b1v, w2v, acc, lse);
  hipLaunchKernelGGL(k_final, dim3(1), dim3(256), 0, stream, acc, lse, (float*)d_out);
}